// Round 1
// baseline (5835.997 us; speedup 1.0000x reference)
//
#include <hip/hip_runtime.h>

typedef __bf16 bf16x8 __attribute__((ext_vector_type(8)));
typedef float f32x4 __attribute__((ext_vector_type(4)));

__device__ __forceinline__ float sigmoidf_fast(float x) {
  return 1.f / (1.f + __expf(-x));
}
__device__ __forceinline__ float tanhf_fast(float x) {
  float e = __expf(2.f * x);
  return 1.f - 2.f / (e + 1.f);
}
__device__ __forceinline__ unsigned pack2(float a, float b) {
  unsigned short ua = __builtin_bit_cast(unsigned short, (__bf16)a);
  unsigned short ub = __builtin_bit_cast(unsigned short, (__bf16)b);
  return (unsigned)ua | ((unsigned)ub << 16);
}

// Wt[tap][oc][ci] = (bf16)W[oc][ci][tap], tap = ky*3+kx  (k-contiguous A rows)
__global__ void transpose_w_kernel(const float* __restrict__ Wsrc,
                                   __bf16* __restrict__ Wt, int C4, int C2) {
  int idx = blockIdx.x * 256 + threadIdx.x;
  int total = C4 * C2 * 9;
  if (idx >= total) return;
  int tap = idx / (C4 * C2);
  int rem = idx - tap * (C4 * C2);
  int oc = rem / C2;
  int ci = rem - oc * C2;
  Wt[idx] = (__bf16)Wsrc[(oc * C2 + ci) * 9 + tap];
}

__global__ void combine_kernel(const float* __restrict__ hf,
                               const float* __restrict__ hb,
                               float* __restrict__ out, int n) {
  int idx = blockIdx.x * 256 + threadIdx.x;
  if (idx >= n) return;
  out[idx] = (hf[idx] + hb[idx]) * 0.5f;
}

// Unified block: 256 threads = 4 waves. M=256 oc (64 ch x 4 gates),
// N=64 px (2 rows x 32 cols). sT = 4 x 34 x 136 bf16 (one 128-ci image
// block), A dbuf = 2 x 256 x 40 bf16 (KC=32 chunks).
// LDS total 77952 B -> TWO blocks per CU (independent barrier domains).
// A prefetch is 2 chunks deep (RA/RB register sets, loop unrolled x2).
constexpr int SMEM_BYTES = 77952;

template <int C, int H, int W, int NCIB>
__device__ __forceinline__ void convlstm_block(
    char* smem, const float* __restrict__ x_t, int maskv,
    const __bf16* __restrict__ Wt, const float* __restrict__ bias,
    const float* __restrict__ h_in, float* __restrict__ h_out,
    float* __restrict__ c_st, int d, int b, int y0, int cs, int x0)
{
  constexpr int Bz = 8, C2 = 2 * C, C4 = 4 * C;
  constexpr int CIB = C2 / NCIB;          // ci per image block = 128
  constexpr int WB = 32, COLS = WB + 2;   // 32-px block + halo
  constexpr int OROWS = 2, IMR = OROWS + 2;
  constexpr int C2p = CIB + 8;            // 136 (16B-aligned rows)
  constexpr int KC = 32, AP = KC + 8;     // 40
  constexpr int ABUF = 256 * AP;          // elems per A buffer
  constexpr int PLANE = H * W, CHW = C * PLANE;
  constexpr int NCHH = 9 * (CIB / KC);    // 36 chunks per ci-half
  constexpr int NCH = NCIB * NCHH;        // 36 or 72 (even)
  constexpr int ITERS = 4;                // A-stage: 16B x 256 thr x 4 = 16KB
  constexpr int WB4 = WB / 4;

  __bf16* sT = (__bf16*)smem;
  __bf16* sA = (__bf16*)(smem + IMR * COLS * C2p * 2);

  const int tid = threadIdx.x;
  const float* hin_b = h_in + (size_t)(d * Bz + b) * CHW;
  float* hout_b = h_out + (size_t)(d * Bz + b) * CHW;

  if (maskv <= 0) {
    // carry this block's 64 channels x 2 rows x 32 px (c untouched)
    for (int u = tid; u < 64 * OROWS * WB4; u += 256) {
      int c = cs * 64 + u / (OROWS * WB4);
      int rem = u % (OROWS * WB4);
      int r = rem / WB4, xu = rem % WB4;
      size_t off = (size_t)c * PLANE + (size_t)(y0 + r) * W + x0 + xu * 4;
      *reinterpret_cast<float4*>(hout_b + off) =
          *reinterpret_cast<const float4*>(hin_b + off);
    }
    return;
  }

  const __bf16* Wtd = Wt + (size_t)d * (9 * C4 * C2);
  const float* x_b = x_t + (size_t)b * CHW;

  // per-thread A-staging constants (slab row aoc = g*64 + c_local)
  int src_off[ITERS], dst_off[ITERS];
#pragma unroll
  for (int it = 0; it < ITERS; ++it) {
    int u = it * 256 + tid;
    int aoc = u >> 2, part = u & 3;       // 4 x 16B parts per 32-elem row
    int gg = aoc >> 6, cl = aoc & 63;
    src_off[it] = (gg * C + cs * 64 + cl) * C2 + part * 8;
    dst_off[it] = aoc * AP + part * 8;
  }

  auto issueA = [&](int c, uint4 (&R)[ITERS]) {
    int cib_c = (NCIB == 2) ? (c / NCHH) : 0;
    int rc = (NCIB == 2) ? (c % NCHH) : c;
    int tap = rc >> 2, kcl = rc & 3;
    size_t choff = (size_t)tap * C4 * C2 + cib_c * CIB + kcl * KC;
#pragma unroll
    for (int it = 0; it < ITERS; ++it)
      R[it] = *reinterpret_cast<const uint4*>(Wtd + choff + src_off[it]);
  };
  auto commitA = [&](uint4 (&R)[ITERS], int bsel) {
    __bf16* dstb = sA + bsel * ABUF;
#pragma unroll
    for (int it = 0; it < ITERS; ++it)
      *reinterpret_cast<uint4*>(dstb + dst_off[it]) = R[it];
  };

  // stage bf16([x | h]) window for one 128-ci block, transposed
  // sT[row][slot][ci_local]; all 34 slots via one loop (zero-fill OOB)
  auto stage_sT = [&](int cib) {
    constexpr int SIT = (CIB / 4) * IMR * COLS / 256;  // 4352/256 = 17
#pragma unroll
    for (int it = 0; it < SIT; ++it) {
      int u = it * 256 + tid;
      int s = u % COLS;
      int t2 = u / COLS;
      int rr = t2 % IMR, ci4 = t2 / IMR;
      int yy = y0 + rr - 1;
      int gx = x0 + s - 1;
      uint2 pv; pv.x = 0u; pv.y = 0u;
      if (yy >= 0 && yy < H && gx >= 0 && gx < W) {
        int ci = cib * CIB + ci4 * 4;
        const float* s0 = ((ci < C) ? (x_b + (size_t)ci * PLANE)
                                    : (hin_b + (size_t)(ci - C) * PLANE)) +
                          (size_t)yy * W + gx;
        pv.x = pack2(s0[0], s0[PLANE]);
        pv.y = pack2(s0[2 * PLANE], s0[3 * PLANE]);
      }
      *reinterpret_cast<uint2*>(&sT[(rr * COLS + s) * C2p + ci4 * 4]) = pv;
    }
  };

  const int lane = tid & 63, wv = tid >> 6;
  const int n = lane & 15, q = lane >> 4;

  f32x4 acc[4][4];
  f32x4 zero = {0.f, 0.f, 0.f, 0.f};
#pragma unroll
  for (int g = 0; g < 4; ++g)
#pragma unroll
    for (int nt = 0; nt < 4; ++nt) acc[g][nt] = zero;

  auto mfma_chunk = [&](int c, int bsel) {
    int rc = (NCIB == 2) ? (c % NCHH) : c;
    int tap = rc >> 2, kcl = rc & 3;
    int ky = tap / 3, kx = tap - 3 * ky;
    bf16x8 bfr[4];
#pragma unroll
    for (int nt = 0; nt < 4; ++nt) {
      int row = (nt >> 1) + ky;
      int slot = (nt & 1) * 16 + n + kx;
      bfr[nt] = *reinterpret_cast<const bf16x8*>(
          &sT[(row * COLS + slot) * C2p + kcl * KC + q * 8]);
    }
    bf16x8 afr[4];
    const __bf16* sAb = sA + bsel * ABUF;
#pragma unroll
    for (int g = 0; g < 4; ++g)
      afr[g] = *reinterpret_cast<const bf16x8*>(
          &sAb[(g * 64 + wv * 16 + n) * AP + q * 8]);
#pragma unroll
    for (int g = 0; g < 4; ++g)
#pragma unroll
      for (int nt = 0; nt < 4; ++nt)
        acc[g][nt] = __builtin_amdgcn_mfma_f32_16x16x32_bf16(
            afr[g], bfr[nt], acc[g][nt], 0, 0, 0);
  };

  // ---- prologue: chunk0 staged directly, chunk1 in flight ----
  uint4 RA[ITERS], RB[ITERS];
  issueA(0, RA);
  stage_sT(0);
  commitA(RA, 0);
  issueA(1, RB);
  __syncthreads();

  // ---- K loop, unrolled x2; chunk c issued at body c-2, committed at
  // end of body c-1 (~2 chunk-times of L2-latency cover) ----
  for (int kc = 0; kc < NCH; kc += 2) {
    if (NCIB == 2 && kc == NCH / 2) {
      stage_sT(1);                       // second ci half
      __syncthreads();
    }
    // even body: reads buf0
    if (kc + 2 < NCH) issueA(kc + 2, RA);
    mfma_chunk(kc, 0);
    commitA(RB, 1);                      // chunk kc+1
    __syncthreads();
    // odd body: reads buf1
    if (kc + 3 < NCH) issueA(kc + 3, RB);
    mfma_chunk(kc + 1, 1);
    if (kc + 2 < NCH) commitA(RA, 0);    // chunk kc+2
    __syncthreads();
  }

  // ---- fused LSTM gate epilogue (D: col = n = px, row = q*4+r = ch) ----
  float* c_b = c_st + (size_t)(d * Bz + b) * CHW;
#pragma unroll
  for (int r = 0; r < 4; ++r) {
    const int cg = cs * 64 + wv * 16 + q * 4 + r;
    const float bi = bias[0 * C + cg];
    const float bff = bias[1 * C + cg];
    const float bo = bias[2 * C + cg];
    const float bg = bias[3 * C + cg];
#pragma unroll
    for (int nt = 0; nt < 4; ++nt) {
      const int y = y0 + (nt >> 1);
      const int x = x0 + (nt & 1) * 16 + n;
      const size_t off = (size_t)cg * PLANE + (size_t)y * W + x;
      const float vi = acc[0][nt][r] + bi;
      const float vf = acc[1][nt][r] + bff;
      const float vo = acc[2][nt][r] + bo;
      const float vg = acc[3][nt][r] + bg;
      const float cn = sigmoidf_fast(vf) * c_b[off] + sigmoidf_fast(vi) * tanhf_fast(vg);
      c_b[off] = cn;
      hout_b[off] = sigmoidf_fast(vo) * tanhf_fast(cn);
    }
  }
}

// blocks [0,512) = level-1 (2 d x 2 cs x 8 b x 16 yb), [512,1536) = level-0
// (2 d x 2 xs x 8 b x 32 yb). dir in the lowest bit -> XCD round-robin.
__global__ __launch_bounds__(256, 2)
void step_kernel(const float* __restrict__ x0, const float* __restrict__ x1,
                 const int* __restrict__ mask_t,
                 const __bf16* __restrict__ Wt0, const __bf16* __restrict__ Wt1,
                 const float* __restrict__ bf0, const float* __restrict__ bb0,
                 const float* __restrict__ bf1, const float* __restrict__ bb1,
                 const float* __restrict__ hin0, float* __restrict__ hout0,
                 float* __restrict__ c0,
                 const float* __restrict__ hin1, float* __restrict__ hout1,
                 float* __restrict__ c1)
{
  __shared__ __align__(16) char smem[SMEM_BYTES];
  const int idx = blockIdx.x;
  if (idx < 512) {
    int d = idx & 1, r = idx >> 1;
    int cs = r & 1; r >>= 1;
    int b = r & 7, yb = r >> 3;          // yb in [0,16): 2 rows each
    convlstm_block<128, 32, 32, 2>(smem, x1, mask_t[b], Wt1,
        d == 0 ? bf1 : bb1, hin1, hout1, c1, d, b, yb * 2, cs, 0);
  } else {
    int j = idx - 512;
    int d = j & 1, r = j >> 1;
    int xs = r & 1; r >>= 1;
    int b = r & 7, yb = r >> 3;          // yb in [0,32): 2 rows each
    convlstm_block<64, 64, 64, 1>(smem, x0, mask_t[b], Wt0,
        d == 0 ? bf0 : bb0, hin0, hout0, c0, d, b, yb * 2, 0, xs * 32);
  }
}

extern "C" void kernel_launch(void* const* d_in, const int* in_sizes, int n_in,
                              void* d_out, int out_size, void* d_ws, size_t ws_size,
                              hipStream_t stream) {
  const float* feat0 = (const float*)d_in[0];
  const float* feat1 = (const float*)d_in[1];
  const int* mask = (const int*)d_in[2];
  const float* Wf0 = (const float*)d_in[3];
  const float* bf0 = (const float*)d_in[4];
  const float* Wb0 = (const float*)d_in[5];
  const float* bb0 = (const float*)d_in[6];
  const float* Wf1 = (const float*)d_in[7];
  const float* bf1 = (const float*)d_in[8];
  const float* Wb1 = (const float*)d_in[9];
  const float* bb1 = (const float*)d_in[10];

  const int T = 16;
  const size_t SZ0 = (size_t)8 * 64 * 64 * 64;   // per-(dir,buf) h elems, level 0
  const size_t SZ1 = (size_t)8 * 128 * 32 * 32;  // level 1
  const size_t WT0 = (size_t)9 * 256 * 128;      // per-dir transposed weights
  const size_t WT1 = (size_t)9 * 512 * 256;

  char* p = (char*)d_ws;
  __bf16* Wt0 = (__bf16*)p; p += 2 * WT0 * sizeof(__bf16);
  __bf16* Wt1 = (__bf16*)p; p += 2 * WT1 * sizeof(__bf16);
  float* h0 = (float*)p;    p += 4 * SZ0 * sizeof(float);   // [buf][dir][B][C][H][W]
  float* h1 = (float*)p;    p += 4 * SZ1 * sizeof(float);
  float* c0 = (float*)p;    p += 2 * SZ0 * sizeof(float);   // [dir][B][C][H][W]
  float* c1 = (float*)p;    p += 2 * SZ1 * sizeof(float);

  hipMemsetAsync(h0, 0, 2 * SZ0 * sizeof(float), stream);
  hipMemsetAsync(h1, 0, 2 * SZ1 * sizeof(float), stream);
  hipMemsetAsync(c0, 0, 2 * SZ0 * sizeof(float), stream);
  hipMemsetAsync(c1, 0, 2 * SZ1 * sizeof(float), stream);

  transpose_w_kernel<<<((int)WT0 + 255) / 256, 256, 0, stream>>>(Wf0, Wt0, 256, 128);
  transpose_w_kernel<<<((int)WT0 + 255) / 256, 256, 0, stream>>>(Wb0, Wt0 + WT0, 256, 128);
  transpose_w_kernel<<<((int)WT1 + 255) / 256, 256, 0, stream>>>(Wf1, Wt1, 512, 256);
  transpose_w_kernel<<<((int)WT1 + 255) / 256, 256, 0, stream>>>(Wb1, Wt1 + WT1, 512, 256);

  for (int t = 0; t < T; ++t) {
    const int pi = t & 1, po = 1 - pi;
    step_kernel<<<1536, 256, 0, stream>>>(
        feat0 + (size_t)t * SZ0, feat1 + (size_t)t * SZ1, mask + t * 8,
        Wt0, Wt1, bf0, bb0, bf1, bb1,
        h0 + (size_t)pi * 2 * SZ0, h0 + (size_t)po * 2 * SZ0, c0,
        h1 + (size_t)pi * 2 * SZ1, h1 + (size_t)po * 2 * SZ1, c1);
  }

  // T=16 is even -> final states live in buf 0
  float* out = (float*)d_out;
  combine_kernel<<<((int)SZ0 + 255) / 256, 256, 0, stream>>>(h0, h0 + SZ0, out, (int)SZ0);
  combine_kernel<<<((int)SZ1 + 255) / 256, 256, 0, stream>>>(h1, h1 + SZ1, out + SZ0, (int)SZ1);
}

// Round 2
// 3417.619 us; speedup vs baseline: 1.7076x; 1.7076x over previous
//
#include <hip/hip_runtime.h>

typedef __bf16 bf16x8 __attribute__((ext_vector_type(8)));
typedef float f32x4 __attribute__((ext_vector_type(4)));

__device__ __forceinline__ float sigmoidf_fast(float x) {
  return 1.f / (1.f + __expf(-x));
}
__device__ __forceinline__ float tanhf_fast(float x) {
  float e = __expf(2.f * x);
  return 1.f - 2.f / (e + 1.f);
}
__device__ __forceinline__ unsigned pack2(float a, float b) {
  unsigned short ua = __builtin_bit_cast(unsigned short, (__bf16)a);
  unsigned short ub = __builtin_bit_cast(unsigned short, (__bf16)b);
  return (unsigned)ua | ((unsigned)ub << 16);
}

// Wt[tap][oc][ci] = (bf16)W[oc][ci][tap], tap = ky*3+kx  (k-contiguous A rows)
__global__ void transpose_w_kernel(const float* __restrict__ Wsrc,
                                   __bf16* __restrict__ Wt, int C4, int C2) {
  int idx = blockIdx.x * 256 + threadIdx.x;
  int total = C4 * C2 * 9;
  if (idx >= total) return;
  int tap = idx / (C4 * C2);
  int rem = idx - tap * (C4 * C2);
  int oc = rem / C2;
  int ci = rem - oc * C2;
  Wt[idx] = (__bf16)Wsrc[(oc * C2 + ci) * 9 + tap];
}

__global__ void combine_kernel(const float* __restrict__ hf,
                               const float* __restrict__ hb,
                               float* __restrict__ out, int n) {
  int idx = blockIdx.x * 256 + threadIdx.x;
  if (idx >= n) return;
  out[idx] = (hf[idx] + hb[idx]) * 0.5f;
}

// Block: 512 thr = 8 waves, 1 block/CU. Per-wave tile M=64 x N=128 px
// (acc 4 gates x 8 nt = 128 VGPR): 12 ds_read_b128 feed 32 MFMAs/chunk
// (0.023 B/FLOP, under the LDS-read roof; round-0's 4x4 tile was 0.061).
// level-0: C=64  -> block M=256, N=256 (4 rows x 64), 4 M-waves x 2 N-waves
// level-1: C=128 -> block M=512 (all oc: A-reuse x2), N=128 (4 x 32),
//                   8 M-waves, ci-split sT with one mid-loop restage
// level-0 LDS: sT 6*66*136*2 = 107712 + A 2*256*40*2 = 40960 -> 148672
// level-1 LDS: sT 6*34*136*2 =  55488 + A 2*512*40*2 = 81920 -> 137408
constexpr int SMEM_BYTES = 148672;

template <int C, int H, int W, int NCIB>
__device__ __forceinline__ void convlstm_block(
    char* smem, const float* __restrict__ x_t, int maskv,
    const __bf16* __restrict__ Wt, const float* __restrict__ bias,
    const float* __restrict__ h_in, float* __restrict__ h_out,
    float* __restrict__ c_st, int d, int b, int y0)
{
  constexpr int Bz = 8, C2 = 2 * C, C4 = 4 * C;
  constexpr int OROWS = 4, IMR = OROWS + 2, COLS = W + 2;
  constexpr int CIB = C2 / NCIB;          // 128 for both levels
  constexpr int C2p = CIB + 8;            // 136
  constexpr int KC = 32, AP = KC + 8;     // 40
  constexpr int MROWS = C4;               // 256 / 512 A-rows per block
  constexpr int ABUF = MROWS * AP;
  constexpr int PLANE = H * W, CHW = C * PLANE;
  constexpr int NCHH = 9 * (CIB / KC);    // 36 chunks per ci-block
  constexpr int NCH = NCIB * NCHH;        // 36 / 72
  constexpr int ITERS = MROWS / 128;      // A-stage: 16B x 512thr per iter
  constexpr int WAVES_M = MROWS / 64;     // 4 / 8
  constexpr int RG = 8 / WAVES_M;         // 2 / 1 N-wave-groups
  constexpr int RPG = OROWS / RG;         // rows per N-group: 2 / 4
  constexpr int NTC = W / 16;             // col-tiles per row: 4 / 2

  __bf16* sT = (__bf16*)smem;
  __bf16* sA = (__bf16*)(smem + IMR * COLS * C2p * 2);

  const int tid = threadIdx.x;
  const float* hin_b = h_in + (size_t)(d * Bz + b) * CHW;
  float* hout_b = h_out + (size_t)(d * Bz + b) * CHW;

  if (maskv <= 0) {
    // carry all C channels x OROWS rows (c untouched)
    for (int u = tid; u < C * OROWS * W / 4; u += 512) {
      int c = u / (OROWS * W / 4);
      int rem = u % (OROWS * W / 4);
      int r = rem / (W / 4), xu = rem % (W / 4);
      size_t off = (size_t)c * PLANE + (size_t)(y0 + r) * W + xu * 4;
      *reinterpret_cast<float4*>(hout_b + off) =
          *reinterpret_cast<const float4*>(hin_b + off);
    }
    return;
  }

  const __bf16* Wtd = Wt + (size_t)d * (9 * C4 * C2);
  const float* x_b = x_t + (size_t)b * CHW;

  // per-thread A-staging constants (A row aoc = g*C + ch, as stored in Wt)
  int src_off[ITERS], dst_off[ITERS];
#pragma unroll
  for (int it = 0; it < ITERS; ++it) {
    int u = it * 512 + tid;
    int aoc = u >> 2, part = u & 3;       // 4 x 16B parts per 32-elem row
    src_off[it] = aoc * C2 + part * 8;
    dst_off[it] = aoc * AP + part * 8;
  }

  uint4 RA[ITERS];
  auto issueA = [&](int c) {
    int cib_c = (NCIB == 2) ? (c / NCHH) : 0;
    int rc = (NCIB == 2) ? (c % NCHH) : c;
    int tap = rc >> 2, kcl = rc & 3;
    size_t choff = (size_t)tap * C4 * C2 + cib_c * CIB + kcl * KC;
#pragma unroll
    for (int it = 0; it < ITERS; ++it)
      RA[it] = *reinterpret_cast<const uint4*>(Wtd + choff + src_off[it]);
  };
  auto commitA = [&](int bsel) {
    __bf16* dstb = sA + bsel * ABUF;
#pragma unroll
    for (int it = 0; it < ITERS; ++it)
      *reinterpret_cast<uint4*>(dstb + dst_off[it]) = RA[it];
  };

  // stage bf16([x | h]) window for one 128-ci block, transposed
  // sT[row][slot][ci_local]; halo slots (OOB) zero-filled in the same loop
  auto stage_sT = [&](int cib) {
    const int total = (CIB / 4) * IMR * COLS;
    for (int u = tid; u < total; u += 512) {
      int s = u % COLS;
      int t2 = u / COLS;
      int rr = t2 % IMR, ci4 = t2 / IMR;
      int yy = y0 + rr - 1;
      int gx = s - 1;
      uint2 pv; pv.x = 0u; pv.y = 0u;
      if (yy >= 0 && yy < H && gx >= 0 && gx < W) {
        int ci = cib * CIB + ci4 * 4;
        const float* s0 = ((ci < C) ? (x_b + (size_t)ci * PLANE)
                                    : (hin_b + (size_t)(ci - C) * PLANE)) +
                          (size_t)yy * W + gx;
        pv.x = pack2(s0[0], s0[PLANE]);
        pv.y = pack2(s0[2 * PLANE], s0[3 * PLANE]);
      }
      *reinterpret_cast<uint2*>(&sT[(rr * COLS + s) * C2p + ci4 * 4]) = pv;
    }
  };

  const int lane = tid & 63, wv = tid >> 6;
  const int wvm = wv % WAVES_M;           // M-slice (16-ch group)
  const int rg = wv / WAVES_M;            // N-group
  const int n = lane & 15, q = lane >> 4;

  f32x4 acc[4][8];
  f32x4 zero = {0.f, 0.f, 0.f, 0.f};
#pragma unroll
  for (int g = 0; g < 4; ++g)
#pragma unroll
    for (int nt = 0; nt < 8; ++nt) acc[g][nt] = zero;

  auto mfma_chunk = [&](int c, int bsel) {
    int rc = (NCIB == 2) ? (c % NCHH) : c;
    int tap = rc >> 2, kcl = rc & 3;
    int ky = tap / 3, kx = tap - 3 * ky;
    bf16x8 bfr[8];
#pragma unroll
    for (int nt = 0; nt < 8; ++nt) {
      int row = rg * RPG + nt / NTC + ky;
      int slot = (nt % NTC) * 16 + n + kx;
      bfr[nt] = *reinterpret_cast<const bf16x8*>(
          &sT[(row * COLS + slot) * C2p + kcl * KC + q * 8]);
    }
    const __bf16* sAb = sA + bsel * ABUF;
#pragma unroll
    for (int g = 0; g < 4; ++g) {
      bf16x8 afr = *reinterpret_cast<const bf16x8*>(
          &sAb[(g * C + wvm * 16 + n) * AP + q * 8]);
#pragma unroll
      for (int nt = 0; nt < 8; ++nt)
        acc[g][nt] = __builtin_amdgcn_mfma_f32_16x16x32_bf16(
            afr, bfr[nt], acc[g][nt], 0, 0, 0);
    }
  };

  // ---- prologue (round-0 pattern: 1-deep A prefetch) ----
  issueA(0);
  stage_sT(0);
  commitA(0);
  __syncthreads();

  for (int kc = 0; kc < NCH; ++kc) {
    if (NCIB == 2 && kc == NCHH) {
      stage_sT(1);                       // second ci half
      __syncthreads();
    }
    if (kc + 1 < NCH) issueA(kc + 1);    // lands during MFMAs below
    mfma_chunk(kc, kc & 1);
    if (kc + 1 < NCH) commitA((kc + 1) & 1);
    __syncthreads();
  }

  // ---- fused LSTM gate epilogue (D: col = n = px, row = q*4+r = ch) ----
  float* c_b = c_st + (size_t)(d * Bz + b) * CHW;
#pragma unroll
  for (int r = 0; r < 4; ++r) {
    const int cg = wvm * 16 + q * 4 + r;
    const float bi = bias[0 * C + cg];
    const float bff = bias[1 * C + cg];
    const float bo = bias[2 * C + cg];
    const float bg = bias[3 * C + cg];
#pragma unroll
    for (int nt = 0; nt < 8; ++nt) {
      const int y = y0 + rg * RPG + nt / NTC;
      const int x = (nt % NTC) * 16 + n;
      const size_t off = (size_t)cg * PLANE + (size_t)y * W + x;
      const float vi = acc[0][nt][r] + bi;
      const float vf = acc[1][nt][r] + bff;
      const float vo = acc[2][nt][r] + bo;
      const float vg = acc[3][nt][r] + bg;
      const float cn = sigmoidf_fast(vf) * c_b[off] + sigmoidf_fast(vi) * tanhf_fast(vg);
      c_b[off] = cn;
      hout_b[off] = sigmoidf_fast(vo) * tanhf_fast(cn);
    }
  }
}

// blocks [0,128) = level-1 (2 d x 8 b x 8 yb) -- long blocks first (LPT
// backfill); [128,384) = level-0 (2 d x 8 b x 16 yb). dir in lowest bit.
__global__ __launch_bounds__(512, 2)
void step_kernel(const float* __restrict__ x0, const float* __restrict__ x1,
                 const int* __restrict__ mask_t,
                 const __bf16* __restrict__ Wt0, const __bf16* __restrict__ Wt1,
                 const float* __restrict__ bf0, const float* __restrict__ bb0,
                 const float* __restrict__ bf1, const float* __restrict__ bb1,
                 const float* __restrict__ hin0, float* __restrict__ hout0,
                 float* __restrict__ c0,
                 const float* __restrict__ hin1, float* __restrict__ hout1,
                 float* __restrict__ c1)
{
  __shared__ __align__(16) char smem[SMEM_BYTES];
  const int idx = blockIdx.x;
  if (idx < 128) {
    int d = idx & 1, r = idx >> 1;
    int b = r & 7, yb = r >> 3;          // yb in [0,8): 4 rows each
    convlstm_block<128, 32, 32, 2>(smem, x1, mask_t[b], Wt1,
        d == 0 ? bf1 : bb1, hin1, hout1, c1, d, b, yb * 4);
  } else {
    int j = idx - 128;
    int d = j & 1, r = j >> 1;
    int b = r & 7, yb = r >> 3;          // yb in [0,16): 4 rows each
    convlstm_block<64, 64, 64, 1>(smem, x0, mask_t[b], Wt0,
        d == 0 ? bf0 : bb0, hin0, hout0, c0, d, b, yb * 4);
  }
}

extern "C" void kernel_launch(void* const* d_in, const int* in_sizes, int n_in,
                              void* d_out, int out_size, void* d_ws, size_t ws_size,
                              hipStream_t stream) {
  const float* feat0 = (const float*)d_in[0];
  const float* feat1 = (const float*)d_in[1];
  const int* mask = (const int*)d_in[2];
  const float* Wf0 = (const float*)d_in[3];
  const float* bf0 = (const float*)d_in[4];
  const float* Wb0 = (const float*)d_in[5];
  const float* bb0 = (const float*)d_in[6];
  const float* Wf1 = (const float*)d_in[7];
  const float* bf1 = (const float*)d_in[8];
  const float* Wb1 = (const float*)d_in[9];
  const float* bb1 = (const float*)d_in[10];

  const int T = 16;
  const size_t SZ0 = (size_t)8 * 64 * 64 * 64;   // per-(dir,buf) h elems, level 0
  const size_t SZ1 = (size_t)8 * 128 * 32 * 32;  // level 1
  const size_t WT0 = (size_t)9 * 256 * 128;      // per-dir transposed weights
  const size_t WT1 = (size_t)9 * 512 * 256;

  char* p = (char*)d_ws;
  __bf16* Wt0 = (__bf16*)p; p += 2 * WT0 * sizeof(__bf16);
  __bf16* Wt1 = (__bf16*)p; p += 2 * WT1 * sizeof(__bf16);
  float* h0 = (float*)p;    p += 4 * SZ0 * sizeof(float);   // [buf][dir][B][C][H][W]
  float* h1 = (float*)p;    p += 4 * SZ1 * sizeof(float);
  float* c0 = (float*)p;    p += 2 * SZ0 * sizeof(float);   // [dir][B][C][H][W]
  float* c1 = (float*)p;    p += 2 * SZ1 * sizeof(float);

  hipMemsetAsync(h0, 0, 2 * SZ0 * sizeof(float), stream);
  hipMemsetAsync(h1, 0, 2 * SZ1 * sizeof(float), stream);
  hipMemsetAsync(c0, 0, 2 * SZ0 * sizeof(float), stream);
  hipMemsetAsync(c1, 0, 2 * SZ1 * sizeof(float), stream);

  transpose_w_kernel<<<((int)WT0 + 255) / 256, 256, 0, stream>>>(Wf0, Wt0, 256, 128);
  transpose_w_kernel<<<((int)WT0 + 255) / 256, 256, 0, stream>>>(Wb0, Wt0 + WT0, 256, 128);
  transpose_w_kernel<<<((int)WT1 + 255) / 256, 256, 0, stream>>>(Wf1, Wt1, 512, 256);
  transpose_w_kernel<<<((int)WT1 + 255) / 256, 256, 0, stream>>>(Wb1, Wt1 + WT1, 512, 256);

  for (int t = 0; t < T; ++t) {
    const int pi = t & 1, po = 1 - pi;
    step_kernel<<<384, 512, 0, stream>>>(
        feat0 + (size_t)t * SZ0, feat1 + (size_t)t * SZ1, mask + t * 8,
        Wt0, Wt1, bf0, bb0, bf1, bb1,
        h0 + (size_t)pi * 2 * SZ0, h0 + (size_t)po * 2 * SZ0, c0,
        h1 + (size_t)pi * 2 * SZ1, h1 + (size_t)po * 2 * SZ1, c1);
  }

  // T=16 is even -> final states live in buf 0
  float* out = (float*)d_out;
  combine_kernel<<<((int)SZ0 + 255) / 256, 256, 0, stream>>>(h0, h0 + SZ0, out, (int)SZ0);
  combine_kernel<<<((int)SZ1 + 255) / 256, 256, 0, stream>>>(h1, h1 + SZ1, out + SZ0, (int)SZ1);
}

// Round 3
// 1889.667 us; speedup vs baseline: 3.0884x; 1.8086x over previous
//
#include <hip/hip_runtime.h>

typedef __bf16 bf16x8 __attribute__((ext_vector_type(8)));
typedef float f32x4 __attribute__((ext_vector_type(4)));

__device__ __forceinline__ float sigmoidf_fast(float x) {
  return 1.f / (1.f + __expf(-x));
}
__device__ __forceinline__ float tanhf_fast(float x) {
  float e = __expf(2.f * x);
  return 1.f - 2.f / (e + 1.f);
}
__device__ __forceinline__ unsigned pack2(float a, float b) {
  unsigned short ua = __builtin_bit_cast(unsigned short, (__bf16)a);
  unsigned short ub = __builtin_bit_cast(unsigned short, (__bf16)b);
  return (unsigned)ua | ((unsigned)ub << 16);
}

// Wt[tap][oc][ci] = (bf16)W[oc][ci][tap], tap = ky*3+kx  (k-contiguous A rows)
__global__ void transpose_w_kernel(const float* __restrict__ Wsrc,
                                   __bf16* __restrict__ Wt, int C4, int C2) {
  int idx = blockIdx.x * 256 + threadIdx.x;
  int total = C4 * C2 * 9;
  if (idx >= total) return;
  int tap = idx / (C4 * C2);
  int rem = idx - tap * (C4 * C2);
  int oc = rem / C2;
  int ci = rem - oc * C2;
  Wt[idx] = (__bf16)Wsrc[(oc * C2 + ci) * 9 + tap];
}

// wbuf[t*8+b] = (index of this active step among b's active steps) & 1
// (write buffer parity; read buffer = 1-w; both buffers zero-init).
// wbuf[128+b] = final buffer parity for the combine.
__global__ void build_wbuf_kernel(const int* __restrict__ mask,
                                  int* __restrict__ wbuf) {
  int b = threadIdx.x;  // 8 threads
  if (b >= 8) return;
  int m = 0;
  for (int t = 0; t < 16; ++t) {
    int w = 0;
    if (mask[t * 8 + b] > 0) { w = m & 1; ++m; }
    wbuf[t * 8 + b] = w;
  }
  wbuf[128 + b] = (m > 0) ? ((m - 1) & 1) : 0;
}

// out = (h[fin][dir0] + h[fin][dir1]) / 2, fin per batch
__global__ void combine_kernel(const float* __restrict__ h,
                               const int* __restrict__ fin,
                               float* __restrict__ out, int n, int chw,
                               size_t SZ) {
  int idx = blockIdx.x * 256 + threadIdx.x;
  if (idx >= n) return;
  int b = idx / chw;
  const float* hb = h + (size_t)fin[b] * 2 * SZ;
  out[idx] = (hb[idx] + hb[SZ + idx]) * 0.5f;
}

// level-1: image 6*34*264*2 = 107712 + A dbuf 2*256*40*2 = 40960  -> 148672
// level-0: image 4*66*136*2 =  71808 + A dbuf 2*256*72*2 = 73728  -> 145536
constexpr int SMEM_BYTES = 148672;

// ===== round-0 proven core (146 us), mask-copy branch removed =====
// Tile = (dir d, c-slice cs of 64 channels, batch b, OROWS rows) -> N=128 px,
// M=256 oc (64 ch x 4 gates). 8 waves = 2 N-groups (rg) x 4 c-waves (wvr).
// K-loop: one barrier per chunk; next chunk's A prefetched into VGPRs during
// MFMAs, ds_written to the other LDS buffer just before the barrier.
template <int C, int H, int W, int OROWS, int KC>
__device__ __forceinline__ void convlstm_block(
    char* smem, const float* __restrict__ x_t,
    const __bf16* __restrict__ Wt, const float* __restrict__ bias,
    const float* __restrict__ h_in, float* __restrict__ h_out,
    float* __restrict__ c_st, int d, int b, int y0, int cs)
{
  constexpr int Bz = 8, C2 = 2 * C, C4 = 4 * C;
  constexpr int COLS = W + 2, C2p = C2 + 8, IMR = OROWS + 2;
  constexpr int PLANE = H * W, CHW = C * PLANE;
  constexpr int AP = KC + 8;          // A-slab k-stride (pad -> 2-way-free reads)
  constexpr int ABUF = 256 * AP;      // elements per A buffer (OCB = 256 rows)
  constexpr int CPK = C2 / KC;        // chunks per tap
  constexpr int NCH = 9 * CPK;
  constexpr int ITERS = KC / 16;      // A-stage: 16B per thread per iter
  constexpr int PPI = KC / 8;         // 16B parts per A row
  constexpr int CTPR = (W / 16) < 4 ? (W / 16) : 4;
  constexpr int RPG = OROWS / 2;
  constexpr int IMG_ITERS = (C2 / 4) * IMR * W / 512;

  __bf16* sT = (__bf16*)smem;
  __bf16* sA = (__bf16*)(smem + (size_t)IMR * COLS * C2p * 2);

  const int tid = threadIdx.x;
  const float* hin_b = h_in + (size_t)(d * Bz + b) * CHW;
  float* hout_b = h_out + (size_t)(d * Bz + b) * CHW;

  const __bf16* Wtd = Wt + (size_t)d * (9 * C4 * C2);

  // per-thread A-staging constants (slab row aoc = g*64 + c_local)
  int src_off[ITERS], dst_off[ITERS];
#pragma unroll
  for (int it = 0; it < ITERS; ++it) {
    int u = it * 512 + tid;
    int aoc = u / PPI, part = u % PPI;
    int gg = aoc >> 6, cl = aoc & 63;
    src_off[it] = (gg * C + cs * 64 + cl) * C2 + part * 8;
    dst_off[it] = aoc * AP + part * 8;
  }

  // issue A chunk-0 loads early
  uint4 aReg[ITERS];
#pragma unroll
  for (int it = 0; it < ITERS; ++it)
    aReg[it] = *reinterpret_cast<const uint4*>(Wtd + src_off[it]);

  // ---- stage bf16([x | h]) window, transposed [row][slot][ci] ----
  const float* x_b = x_t + (size_t)b * CHW;
#pragma unroll
  for (int it = 0; it < IMG_ITERS; ++it) {
    int u = it * 512 + tid;
    int x = u % W;
    int t2 = u / W;
    int rr = t2 % IMR, ci4 = t2 / IMR;
    int yy = y0 + rr - 1;
    uint2 pv; pv.x = 0u; pv.y = 0u;
    if (yy >= 0 && yy < H) {
      int ci = ci4 * 4;
      const float* s0 = ((ci < C) ? (x_b + (size_t)ci * PLANE)
                                  : (hin_b + (size_t)(ci - C) * PLANE)) +
                        (size_t)yy * W + x;
      float f0 = s0[0];
      float f1 = s0[PLANE];
      float f2 = s0[2 * PLANE];
      float f3 = s0[3 * PLANE];
      pv.x = pack2(f0, f1);
      pv.y = pack2(f2, f3);
    }
    *reinterpret_cast<uint2*>(&sT[(rr * COLS + x + 1) * C2p + ci4 * 4]) = pv;
  }
  // x halo: slots 0 and W+1 zero
  for (int u = tid; u < (C2 / 4) * IMR * 2; u += 512) {
    int ci4 = u / (IMR * 2);
    int rem = u % (IMR * 2);
    int rr = rem >> 1;
    int slot = (rem & 1) ? (W + 1) : 0;
    uint2 z; z.x = 0u; z.y = 0u;
    *reinterpret_cast<uint2*>(&sT[(rr * COLS + slot) * C2p + ci4 * 4]) = z;
  }
  // commit A chunk 0
#pragma unroll
  for (int it = 0; it < ITERS; ++it)
    *reinterpret_cast<uint4*>(sA + dst_off[it]) = aReg[it];
  __syncthreads();

  const int lane = tid & 63, wv = tid >> 6;
  const int rg = wv >> 2, wvr = wv & 3;
  const int n = lane & 15, q = lane >> 4;

  f32x4 acc[4][4];
  f32x4 zero = {0.f, 0.f, 0.f, 0.f};
#pragma unroll
  for (int g = 0; g < 4; ++g)
#pragma unroll
    for (int nt = 0; nt < 4; ++nt) acc[g][nt] = zero;

  for (int kc = 0; kc < NCH; ++kc) {
    const int tap = kc / CPK, ci0 = (kc % CPK) * KC;
    const int ky = tap / 3, kx = tap - 3 * ky;

    // prefetch next chunk's A into VGPRs (lands during MFMAs below)
    if (kc + 1 < NCH) {
      int ntap = (kc + 1) / CPK, nci0 = ((kc + 1) % CPK) * KC;
      size_t choff = (size_t)ntap * C4 * C2 + nci0;
#pragma unroll
      for (int it = 0; it < ITERS; ++it)
        aReg[it] = *reinterpret_cast<const uint4*>(Wtd + choff + src_off[it]);
    }

    const __bf16* sAb = sA + (kc & 1) * ABUF;
#pragma unroll
    for (int kk = 0; kk < KC / 32; ++kk) {
      bf16x8 bfr[4];
#pragma unroll
      for (int nt = 0; nt < 4; ++nt) {
        int row = rg * RPG + nt / CTPR + ky;
        int slot = (nt % CTPR) * 16 + n + kx;
        bfr[nt] = *reinterpret_cast<const bf16x8*>(
            &sT[(row * COLS + slot) * C2p + ci0 + kk * 32 + q * 8]);
      }
      bf16x8 afr[4];
#pragma unroll
      for (int g = 0; g < 4; ++g)
        afr[g] = *reinterpret_cast<const bf16x8*>(
            &sAb[(g * 64 + wvr * 16 + n) * AP + kk * 32 + q * 8]);
#pragma unroll
      for (int g = 0; g < 4; ++g)
#pragma unroll
        for (int nt = 0; nt < 4; ++nt)
          acc[g][nt] = __builtin_amdgcn_mfma_f32_16x16x32_bf16(
              afr[g], bfr[nt], acc[g][nt], 0, 0, 0);
    }

    // commit prefetched A to the other buffer (vmcnt wait lands here, late)
    if (kc + 1 < NCH) {
      __bf16* sAn = sA + ((kc + 1) & 1) * ABUF;
#pragma unroll
      for (int it = 0; it < ITERS; ++it)
        *reinterpret_cast<uint4*>(sAn + dst_off[it]) = aReg[it];
    }
    __syncthreads();
  }

  // ---- fused LSTM gate epilogue (D: col = n = px, row = q*4+r = channel) ----
  float* c_b = c_st + (size_t)(d * Bz + b) * CHW;
#pragma unroll
  for (int r = 0; r < 4; ++r) {
    const int cg = cs * 64 + wvr * 16 + q * 4 + r;
    const float bi = bias[0 * C + cg];
    const float bff = bias[1 * C + cg];
    const float bo = bias[2 * C + cg];
    const float bg = bias[3 * C + cg];
#pragma unroll
    for (int nt = 0; nt < 4; ++nt) {
      const int y = y0 + rg * RPG + nt / CTPR;
      const int x = (nt % CTPR) * 16 + n;
      const size_t off = (size_t)cg * PLANE + (size_t)y * W + x;
      const float vi = acc[0][nt][r] + bi;
      const float vf = acc[1][nt][r] + bff;
      const float vo = acc[2][nt][r] + bo;
      const float vg = acc[3][nt][r] + bg;
      const float cn = sigmoidf_fast(vf) * c_b[off] + sigmoidf_fast(vi) * tanhf_fast(vg);
      c_b[off] = cn;
      hout_b[off] = sigmoidf_fast(vo) * tanhf_fast(cn);
    }
  }
}

// Persistent blocks (grid=256, one per CU) pop tile ids 0..767 from a
// per-step atomic counter. Tiles [0,256) = level-1 (2x heavier -> LPT
// first): 2 d x 2 cs x 8 b x 8 yb; [256,768) = level-0: 2 d x 8 b x 32 yb.
// Masked (t,b) tiles are NO-OPS: h ping-pongs on active steps only
// (write parity from wbuf), c updated in place.
__global__ __launch_bounds__(512, 2)
void step_kernel(const float* __restrict__ x0, const float* __restrict__ x1,
                 const int* __restrict__ mask_t, const int* __restrict__ wbuf_t,
                 int* __restrict__ counter,
                 const __bf16* __restrict__ Wt0, const __bf16* __restrict__ Wt1,
                 const float* __restrict__ bf0, const float* __restrict__ bb0,
                 const float* __restrict__ bf1, const float* __restrict__ bb1,
                 float* __restrict__ h0, float* __restrict__ c0,
                 float* __restrict__ h1, float* __restrict__ c1)
{
  __shared__ __align__(16) char smem[SMEM_BYTES];
  __shared__ int s_pop;
  constexpr size_t SZ0 = (size_t)8 * 64 * 64 * 64;
  constexpr size_t SZ1 = (size_t)8 * 128 * 32 * 32;

  for (;;) {
    __syncthreads();                       // protects s_pop + smem reuse
    if (threadIdx.x == 0) s_pop = atomicAdd(counter, 1);
    __syncthreads();
    const int idx = s_pop;
    if (idx >= 768) return;

    if (idx < 256) {
      int d = idx & 1, r = idx >> 1;
      int cs = r & 1; r >>= 1;
      int b = r & 7, yb = r >> 3;          // yb in [0,8): 4 rows each
      if (mask_t[b] <= 0) continue;
      int w = wbuf_t[b];
      convlstm_block<128, 32, 32, 4, 32>(smem, x1, Wt1,
          d == 0 ? bf1 : bb1,
          h1 + (size_t)(1 - w) * 2 * SZ1, h1 + (size_t)w * 2 * SZ1,
          c1, d, b, yb * 4, cs);
    } else {
      int j = idx - 256;
      int d = j & 1, r = j >> 1;
      int b = r & 7, yb = r >> 3;          // yb in [0,32): 2 rows each
      if (mask_t[b] <= 0) continue;
      int w = wbuf_t[b];
      convlstm_block<64, 64, 64, 2, 64>(smem, x0, Wt0,
          d == 0 ? bf0 : bb0,
          h0 + (size_t)(1 - w) * 2 * SZ0, h0 + (size_t)w * 2 * SZ0,
          c0, d, b, yb * 2, 0);
    }
  }
}

extern "C" void kernel_launch(void* const* d_in, const int* in_sizes, int n_in,
                              void* d_out, int out_size, void* d_ws, size_t ws_size,
                              hipStream_t stream) {
  const float* feat0 = (const float*)d_in[0];
  const float* feat1 = (const float*)d_in[1];
  const int* mask = (const int*)d_in[2];
  const float* Wf0 = (const float*)d_in[3];
  const float* bf0 = (const float*)d_in[4];
  const float* Wb0 = (const float*)d_in[5];
  const float* bb0 = (const float*)d_in[6];
  const float* Wf1 = (const float*)d_in[7];
  const float* bf1 = (const float*)d_in[8];
  const float* Wb1 = (const float*)d_in[9];
  const float* bb1 = (const float*)d_in[10];

  const int T = 16;
  const size_t SZ0 = (size_t)8 * 64 * 64 * 64;   // per-(dir,buf) h elems, level 0
  const size_t SZ1 = (size_t)8 * 128 * 32 * 32;  // level 1
  const size_t WT0 = (size_t)9 * 256 * 128;      // per-dir transposed weights
  const size_t WT1 = (size_t)9 * 512 * 256;

  char* p = (char*)d_ws;
  __bf16* Wt0 = (__bf16*)p; p += 2 * WT0 * sizeof(__bf16);
  __bf16* Wt1 = (__bf16*)p; p += 2 * WT1 * sizeof(__bf16);
  float* h0 = (float*)p;    p += 4 * SZ0 * sizeof(float);   // [buf][dir][B][C][H][W]
  float* h1 = (float*)p;    p += 4 * SZ1 * sizeof(float);
  float* c0 = (float*)p;    p += 2 * SZ0 * sizeof(float);   // [dir][B][C][H][W]
  float* c1 = (float*)p;    p += 2 * SZ1 * sizeof(float);
  int* wbuf = (int*)p;      p += 256 * sizeof(int);         // [16][8] + fin[8]
  int* counters = (int*)p;  p += 16 * sizeof(int);

  hipMemsetAsync(h0, 0, 4 * SZ0 * sizeof(float), stream);
  hipMemsetAsync(h1, 0, 4 * SZ1 * sizeof(float), stream);
  hipMemsetAsync(c0, 0, 2 * SZ0 * sizeof(float), stream);
  hipMemsetAsync(c1, 0, 2 * SZ1 * sizeof(float), stream);
  hipMemsetAsync(counters, 0, 16 * sizeof(int), stream);

  transpose_w_kernel<<<((int)WT0 + 255) / 256, 256, 0, stream>>>(Wf0, Wt0, 256, 128);
  transpose_w_kernel<<<((int)WT0 + 255) / 256, 256, 0, stream>>>(Wb0, Wt0 + WT0, 256, 128);
  transpose_w_kernel<<<((int)WT1 + 255) / 256, 256, 0, stream>>>(Wf1, Wt1, 512, 256);
  transpose_w_kernel<<<((int)WT1 + 255) / 256, 256, 0, stream>>>(Wb1, Wt1 + WT1, 512, 256);
  build_wbuf_kernel<<<1, 8, 0, stream>>>(mask, wbuf);

  for (int t = 0; t < T; ++t) {
    step_kernel<<<256, 512, 0, stream>>>(
        feat0 + (size_t)t * SZ0, feat1 + (size_t)t * SZ1,
        mask + t * 8, wbuf + t * 8, counters + t,
        Wt0, Wt1, bf0, bb0, bf1, bb1,
        h0, c0, h1, c1);
  }

  float* out = (float*)d_out;
  combine_kernel<<<((int)SZ0 + 255) / 256, 256, 0, stream>>>(
      h0, wbuf + 128, out, (int)SZ0, 64 * 64 * 64, SZ0);
  combine_kernel<<<((int)SZ1 + 255) / 256, 256, 0, stream>>>(
      h1, wbuf + 128, out + SZ0, (int)SZ1, 128 * 32 * 32, SZ1);
}

// Round 4
// 1296.805 us; speedup vs baseline: 4.5003x; 1.4572x over previous
//
#include <hip/hip_runtime.h>

typedef __bf16 bf16x8 __attribute__((ext_vector_type(8)));
typedef float f32x4 __attribute__((ext_vector_type(4)));

__device__ __forceinline__ float sigmoidf_fast(float x) {
  return 1.f / (1.f + __expf(-x));
}
__device__ __forceinline__ float tanhf_fast(float x) {
  float e = __expf(2.f * x);
  return 1.f - 2.f / (e + 1.f);
}
__device__ __forceinline__ unsigned pack2(float a, float b) {
  unsigned short ua = __builtin_bit_cast(unsigned short, (__bf16)a);
  unsigned short ub = __builtin_bit_cast(unsigned short, (__bf16)b);
  return (unsigned)ua | ((unsigned)ub << 16);
}

// Fragment-major weight pack: Wt[(((tap*SLT + sl)*4 + q)*C4 + oc)*8 + j]
// = W[oc][ci][tap], ci = sl*32 + q*8 + j. A wave's 16-row x 16B A-fragment
// load is then 4 x 256B fully-used segments (coalesced global dwordx4).
__global__ void transpose_w_kernel(const float* __restrict__ Wsrc,
                                   __bf16* __restrict__ Wt, int C4, int C2) {
  int idx = blockIdx.x * 256 + threadIdx.x;
  int total = C4 * C2 * 9;
  if (idx >= total) return;
  int SLT = C2 >> 5;
  int j = idx & 7;
  int e = idx >> 3;
  int oc = e % C4; e /= C4;
  int q = e & 3;   e >>= 2;
  int sl = e % SLT;
  int tap = e / SLT;
  int ci = sl * 32 + q * 8 + j;
  Wt[idx] = (__bf16)Wsrc[(oc * C2 + ci) * 9 + tap];
}

// wbuf[t*8+b] = write-buffer parity of active step (read = 1-w); both
// buffers zero-init. wbuf[128+b] = final parity for the combine.
__global__ void build_wbuf_kernel(const int* __restrict__ mask,
                                  int* __restrict__ wbuf) {
  int b = threadIdx.x;  // 8 threads
  if (b >= 8) return;
  int m = 0;
  for (int t = 0; t < 16; ++t) {
    int w = 0;
    if (mask[t * 8 + b] > 0) { w = m & 1; ++m; }
    wbuf[t * 8 + b] = w;
  }
  wbuf[128 + b] = (m > 0) ? ((m - 1) & 1) : 0;
}

// out = (h[fin][dir0] + h[fin][dir1]) / 2, fin per batch
__global__ void combine_kernel(const float* __restrict__ h,
                               const int* __restrict__ fin,
                               float* __restrict__ out, int n, int chw,
                               size_t SZ) {
  int idx = blockIdx.x * 256 + threadIdx.x;
  if (idx >= n) return;
  int b = idx / chw;
  const float* hb = h + (size_t)fin[b] * 2 * SZ;
  out[idx] = (hb[idx] + hb[SZ + idx]) * 0.5f;
}

// LDS = image tile only (A goes global->VGPR directly; K-loop barrier-free)
// level-1: sT 6*34*264*2 = 107712 (full 256 ci, no restage)
// level-0: sT 4*66*136*2 =  71808
constexpr int SMEM_BYTES = 107712;

// Tile = (dir d, 64-ch slice cs, batch b, OROWS rows): N = OROWS*W px,
// M = 256 oc (64 ch x 4 gates). 8 waves = 2 N-groups (rg) x 4 ch-waves
// (wvr). K-loop: per 32-k slice each wave loads its A fragments straight
// from global (fragment-major pack, L2-resident) + B from sT; 2-deep
// register pipeline (A0/B0, A1/B1); NO barriers, NO LDS writes in loop.
template <int C, int H, int W, int OROWS>
__device__ __forceinline__ void convlstm_block(
    char* smem, const float* __restrict__ x_t,
    const __bf16* __restrict__ Wt, const float* __restrict__ bias,
    const float* __restrict__ h_in, float* __restrict__ h_out,
    float* __restrict__ c_st, int d, int b, int y0, int cs)
{
  constexpr int Bz = 8, C2 = 2 * C, C4 = 4 * C;
  constexpr int COLS = W + 2, C2p = C2 + 8, IMR = OROWS + 2;
  constexpr int PLANE = H * W, CHW = C * PLANE;
  constexpr int SLT = C2 / 32;            // 32-k slices per tap: 4 / 8
  constexpr int LSLT = (SLT == 4) ? 2 : 3;
  constexpr int NSL = 9 * SLT;            // 36 / 72 (even)
  constexpr int ASL = 32 * C4;            // A elements per slice
  constexpr int CTPR = (W / 16) < 4 ? (W / 16) : 4;
  constexpr int RPG = OROWS / 2;
  constexpr int IMG_ITERS = (C2 / 4) * IMR * W / 512;

  __bf16* sT = (__bf16*)smem;

  const int tid = threadIdx.x;
  const float* hin_b = h_in + (size_t)(d * Bz + b) * CHW;
  float* hout_b = h_out + (size_t)(d * Bz + b) * CHW;
  const __bf16* Wtd = Wt + (size_t)d * (9 * C4 * C2);

  const int lane = tid & 63, wv = tid >> 6;
  const int rg = wv >> 2, wvr = wv & 3;
  const int n = lane & 15, q = lane >> 4;

  // wave-sliced A base: oc = g*C + cs*64 + wvr*16 + n, k-slot q
  const __bf16* Ap = Wtd + (size_t)(q * C4 + cs * 64 + wvr * 16 + n) * 8;

  uint4 A0[4], A1[4];
  auto loadA = [&](int sl, uint4 (&A)[4]) {
    const __bf16* p = Ap + (size_t)sl * ASL;
#pragma unroll
    for (int g = 0; g < 4; ++g)
      A[g] = *reinterpret_cast<const uint4*>(p + g * (C * 8));
  };

  // issue first two A slices before staging (lands under the stage)
  loadA(0, A0);
  loadA(1, A1);

  // ---- stage bf16([x | h]) window, transposed [row][slot][ci] ----
  const float* x_b = x_t + (size_t)b * CHW;
#pragma unroll
  for (int it = 0; it < IMG_ITERS; ++it) {
    int u = it * 512 + tid;
    int x = u % W;
    int t2 = u / W;
    int rr = t2 % IMR, ci4 = t2 / IMR;
    int yy = y0 + rr - 1;
    uint2 pv; pv.x = 0u; pv.y = 0u;
    if (yy >= 0 && yy < H) {
      int ci = ci4 * 4;
      const float* s0 = ((ci < C) ? (x_b + (size_t)ci * PLANE)
                                  : (hin_b + (size_t)(ci - C) * PLANE)) +
                        (size_t)yy * W + x;
      float f0 = s0[0];
      float f1 = s0[PLANE];
      float f2 = s0[2 * PLANE];
      float f3 = s0[3 * PLANE];
      pv.x = pack2(f0, f1);
      pv.y = pack2(f2, f3);
    }
    *reinterpret_cast<uint2*>(&sT[(rr * COLS + x + 1) * C2p + ci4 * 4]) = pv;
  }
  // x halo: slots 0 and W+1 zero
  for (int u = tid; u < (C2 / 4) * IMR * 2; u += 512) {
    int ci4 = u / (IMR * 2);
    int rem = u % (IMR * 2);
    int rr = rem >> 1;
    int slot = (rem & 1) ? (W + 1) : 0;
    uint2 z; z.x = 0u; z.y = 0u;
    *reinterpret_cast<uint2*>(&sT[(rr * COLS + slot) * C2p + ci4 * 4]) = z;
  }
  __syncthreads();

  f32x4 acc[4][4];
  f32x4 zero = {0.f, 0.f, 0.f, 0.f};
#pragma unroll
  for (int g = 0; g < 4; ++g)
#pragma unroll
    for (int nt = 0; nt < 4; ++nt) acc[g][nt] = zero;

  auto loadB = [&](int sl, bf16x8 (&Bv)[4]) {
    int tap = sl >> LSLT;
    int ci0 = (sl & (SLT - 1)) * 32;
    int ky = (tap * 11) >> 5;           // tap/3 for tap in [0,9)
    int kx = tap - 3 * ky;
#pragma unroll
    for (int nt = 0; nt < 4; ++nt) {
      int row = rg * RPG + nt / CTPR + ky;
      int slot = (nt % CTPR) * 16 + n + kx;
      Bv[nt] = *reinterpret_cast<const bf16x8*>(
          &sT[(row * COLS + slot) * C2p + ci0 + q * 8]);
    }
  };
  auto mfmaAll = [&](uint4 (&A)[4], bf16x8 (&Bv)[4]) {
#pragma unroll
    for (int g = 0; g < 4; ++g) {
      bf16x8 a = __builtin_bit_cast(bf16x8, A[g]);
#pragma unroll
      for (int nt = 0; nt < 4; ++nt)
        acc[g][nt] = __builtin_amdgcn_mfma_f32_16x16x32_bf16(
            a, Bv[nt], acc[g][nt], 0, 0, 0);
    }
  };

  bf16x8 B0[4], B1[4];
  loadB(0, B0);
  loadB(1, B1);
  for (int sl = 0; sl < NSL - 2; sl += 2) {
    mfmaAll(A0, B0);
    loadA(sl + 2, A0);
    loadB(sl + 2, B0);
    mfmaAll(A1, B1);
    loadA(sl + 3, A1);
    loadB(sl + 3, B1);
  }
  mfmaAll(A0, B0);
  mfmaAll(A1, B1);

  // ---- fused LSTM gate epilogue (D: col = n = px, row = q*4+r = channel) ----
  float* c_b = c_st + (size_t)(d * Bz + b) * CHW;
#pragma unroll
  for (int r = 0; r < 4; ++r) {
    const int cg = cs * 64 + wvr * 16 + q * 4 + r;
    const float bi = bias[0 * C + cg];
    const float bff = bias[1 * C + cg];
    const float bo = bias[2 * C + cg];
    const float bg = bias[3 * C + cg];
#pragma unroll
    for (int nt = 0; nt < 4; ++nt) {
      const int y = y0 + rg * RPG + nt / CTPR;
      const int x = (nt % CTPR) * 16 + n;
      const size_t off = (size_t)cg * PLANE + (size_t)y * W + x;
      const float vi = acc[0][nt][r] + bi;
      const float vf = acc[1][nt][r] + bff;
      const float vo = acc[2][nt][r] + bo;
      const float vg = acc[3][nt][r] + bg;
      const float cn = sigmoidf_fast(vf) * c_b[off] + sigmoidf_fast(vi) * tanhf_fast(vg);
      c_b[off] = cn;
      hout_b[off] = sigmoidf_fast(vo) * tanhf_fast(cn);
    }
  }
}

// Persistent blocks (grid=256, one per CU) pop tiles 0..767 per step.
// Ordering: level-1 first (2x heavier, LPT), grouped (d,cs)-major for
// weight-panel L2 temporal locality; level-0 grouped d-major.
// Masked (t,b) tiles are no-ops (h ping-pongs on active steps, c in place).
__global__ __launch_bounds__(512, 2)
void step_kernel(const float* __restrict__ x0, const float* __restrict__ x1,
                 const int* __restrict__ mask_t, const int* __restrict__ wbuf_t,
                 int* __restrict__ counter,
                 const __bf16* __restrict__ Wt0, const __bf16* __restrict__ Wt1,
                 const float* __restrict__ bf0, const float* __restrict__ bb0,
                 const float* __restrict__ bf1, const float* __restrict__ bb1,
                 float* __restrict__ h0, float* __restrict__ c0,
                 float* __restrict__ h1, float* __restrict__ c1)
{
  __shared__ __align__(16) char smem[SMEM_BYTES];
  __shared__ int s_pop;
  constexpr size_t SZ0 = (size_t)8 * 64 * 64 * 64;
  constexpr size_t SZ1 = (size_t)8 * 128 * 32 * 32;

  for (;;) {
    __syncthreads();                       // smem reuse + s_pop protection
    if (threadIdx.x == 0) s_pop = atomicAdd(counter, 1);
    __syncthreads();
    const int idx = s_pop;
    if (idx >= 768) return;

    if (idx < 256) {
      int grp = idx >> 6;                  // (d,cs)-major
      int d = grp >> 1, cs = grp & 1;
      int r = idx & 63;
      int b = r & 7, yb = r >> 3;          // yb in [0,8): 4 rows each
      if (mask_t[b] <= 0) continue;
      int w = wbuf_t[b];
      convlstm_block<128, 32, 32, 4>(smem, x1, Wt1,
          d == 0 ? bf1 : bb1,
          h1 + (size_t)(1 - w) * 2 * SZ1, h1 + (size_t)w * 2 * SZ1,
          c1, d, b, yb * 4, cs);
    } else {
      int j = idx - 256;
      int d = j >> 8;                      // d-major
      int r = j & 255;
      int b = r & 7, yb = r >> 3;          // yb in [0,32): 2 rows each
      if (mask_t[b] <= 0) continue;
      int w = wbuf_t[b];
      convlstm_block<64, 64, 64, 2>(smem, x0, Wt0,
          d == 0 ? bf0 : bb0,
          h0 + (size_t)(1 - w) * 2 * SZ0, h0 + (size_t)w * 2 * SZ0,
          c0, d, b, yb * 2, 0);
    }
  }
}

extern "C" void kernel_launch(void* const* d_in, const int* in_sizes, int n_in,
                              void* d_out, int out_size, void* d_ws, size_t ws_size,
                              hipStream_t stream) {
  const float* feat0 = (const float*)d_in[0];
  const float* feat1 = (const float*)d_in[1];
  const int* mask = (const int*)d_in[2];
  const float* Wf0 = (const float*)d_in[3];
  const float* bf0 = (const float*)d_in[4];
  const float* Wb0 = (const float*)d_in[5];
  const float* bb0 = (const float*)d_in[6];
  const float* Wf1 = (const float*)d_in[7];
  const float* bf1 = (const float*)d_in[8];
  const float* Wb1 = (const float*)d_in[9];
  const float* bb1 = (const float*)d_in[10];

  const int T = 16;
  const size_t SZ0 = (size_t)8 * 64 * 64 * 64;   // per-(dir,buf) h elems, level 0
  const size_t SZ1 = (size_t)8 * 128 * 32 * 32;  // level 1
  const size_t WT0 = (size_t)9 * 256 * 128;      // per-dir packed weights
  const size_t WT1 = (size_t)9 * 512 * 256;

  char* p = (char*)d_ws;
  __bf16* Wt0 = (__bf16*)p; p += 2 * WT0 * sizeof(__bf16);
  __bf16* Wt1 = (__bf16*)p; p += 2 * WT1 * sizeof(__bf16);
  float* h0 = (float*)p;    p += 4 * SZ0 * sizeof(float);   // [buf][dir][B][C][H][W]
  float* h1 = (float*)p;    p += 4 * SZ1 * sizeof(float);
  float* c0 = (float*)p;    p += 2 * SZ0 * sizeof(float);   // [dir][B][C][H][W]
  float* c1 = (float*)p;    p += 2 * SZ1 * sizeof(float);
  int* wbuf = (int*)p;      p += 256 * sizeof(int);         // [16][8] + fin[8]
  int* counters = (int*)p;  p += 16 * sizeof(int);

  hipMemsetAsync(h0, 0, 4 * SZ0 * sizeof(float), stream);
  hipMemsetAsync(h1, 0, 4 * SZ1 * sizeof(float), stream);
  hipMemsetAsync(c0, 0, 2 * SZ0 * sizeof(float), stream);
  hipMemsetAsync(c1, 0, 2 * SZ1 * sizeof(float), stream);
  hipMemsetAsync(counters, 0, 16 * sizeof(int), stream);

  transpose_w_kernel<<<((int)WT0 + 255) / 256, 256, 0, stream>>>(Wf0, Wt0, 256, 128);
  transpose_w_kernel<<<((int)WT0 + 255) / 256, 256, 0, stream>>>(Wb0, Wt0 + WT0, 256, 128);
  transpose_w_kernel<<<((int)WT1 + 255) / 256, 256, 0, stream>>>(Wf1, Wt1, 512, 256);
  transpose_w_kernel<<<((int)WT1 + 255) / 256, 256, 0, stream>>>(Wb1, Wt1 + WT1, 512, 256);
  build_wbuf_kernel<<<1, 8, 0, stream>>>(mask, wbuf);

  for (int t = 0; t < T; ++t) {
    step_kernel<<<256, 512, 0, stream>>>(
        feat0 + (size_t)t * SZ0, feat1 + (size_t)t * SZ1,
        mask + t * 8, wbuf + t * 8, counters + t,
        Wt0, Wt1, bf0, bb0, bf1, bb1,
        h0, c0, h1, c1);
  }

  float* out = (float*)d_out;
  combine_kernel<<<((int)SZ0 + 255) / 256, 256, 0, stream>>>(
      h0, wbuf + 128, out, (int)SZ0, 64 * 64 * 64, SZ0);
  combine_kernel<<<((int)SZ1 + 255) / 256, 256, 0, stream>>>(
      h1, wbuf + 128, out + SZ0, (int)SZ1, 128 * 32 * 32, SZ1);
}